// Round 3
// baseline (168.818 us; speedup 1.0000x reference)
//
#include <hip/hip_runtime.h>
#include <hip/hip_bf16.h>

#define NN  1024
#define HH  64
#define DYF 0.0009765625f            // 1/1024
#define SCL 2.8853900817779268f      // 2*log2(e): tanh(x) = 1 - 2/(2^(SCL*x)+1)
#define JC  8

typedef __attribute__((ext_vector_type(4)))  float f32x4;
typedef __attribute__((ext_vector_type(16))) float f32x16;
typedef __attribute__((ext_vector_type(8)))  short bf16x8s;

__device__ __forceinline__ float tfast(float x) {
  float e = __expf(2.0f * x);
  return 1.0f - __fdividef(2.0f, e + 1.0f);
}

// ---------------- fused prep ------------------------------------------------
// blocks 0..63 : Ap[i][m] = SCL*yi*W1[0][m]; Cp[j][m] = SCL*(yj*W1[1][m]+b1[m])
//                W2f = bf16(-2*SCL*W2) in B-fragment order
// blocks 64..67: out[i] = hom[i] + Hb2 + (b3 + sum(W3)) * G * DY   (G = sum f)
// block  68    : b2c[l] = SCL*(b2[l] + sum_m W2[m][l])
__global__ __launch_bounds__(256) void prep_kernel(
    const float* __restrict__ ys, const float* __restrict__ W1,
    const float* __restrict__ b1, const float* __restrict__ W2,
    const float* __restrict__ b2, const float* __restrict__ W3,
    const float* __restrict__ b3, const float* __restrict__ f,
    const float* __restrict__ Hw1, const float* __restrict__ Hb1,
    const float* __restrict__ Hw2, const float* __restrict__ Hb2,
    float* __restrict__ Ap, float* __restrict__ Cp,
    ushort* __restrict__ W2f, float* __restrict__ b2c,
    float* __restrict__ out)
{
  __shared__ float red[256];
  const int blk = blockIdx.x, t = threadIdx.x;

  if (blk < 64) {
    int gt = blk * 256 + t;                 // 0..16383
    int row = gt >> 4, part = gt & 15;
    float y = ys[row];
    #pragma unroll
    for (int q = 0; q < 4; ++q) {
      int m = part * 4 + q;
      Ap[row * HH + m] = SCL * y * W1[m];                    // W1[0][m]
      Cp[row * HH + m] = SCL * fmaf(y, W1[HH + m], b1[m]);   // W1[1][m]
    }
    if (gt < 4096) {
      // flat = (((tile*4+ks)*2+h)*32 + c)*8 + e ; val = -2*SCL*W2[k][tile*32+c]
      int e = gt & 7, c = (gt >> 3) & 31, h = (gt >> 8) & 1, ks = (gt >> 9) & 3, tl = gt >> 11;
      int k = ks * 16 + h * 8 + e;
      float v = -2.0f * SCL * W2[k * HH + tl * 32 + c];
      __hip_bfloat16 hb = __float2bfloat16(v);
      W2f[gt] = *reinterpret_cast<ushort*>(&hb);
    }
  } else if (blk < 68) {
    float4 fv = ((const float4*)f)[t];
    red[t] = fv.x + fv.y + fv.z + fv.w;
    __syncthreads();
    for (int s = 128; s > 0; s >>= 1) {
      if (t < s) red[t] += red[t + s];
      __syncthreads();
    }
    float G = red[0];
    int i = (blk - 64) * 256 + t;
    float y = ys[i];
    float hom = 0.0f, sw3 = 0.0f;
    #pragma unroll
    for (int l = 0; l < HH; ++l) {
      hom += Hw2[l] * tfast(fmaf(y, Hw1[l], Hb1[l]));
      sw3 += W3[l];
    }
    out[i] = hom + Hb2[0] + (b3[0] + sw3) * G * DYF;
  } else {
    if (t < HH) {
      float cs = 0.0f;
      #pragma unroll
      for (int m = 0; m < HH; ++m) cs += W2[m * HH + t];
      b2c[t] = SCL * (b2[t] + cs);
    }
  }
}

// ---------------- main: wave = 32 i's, loop over JC j's ---------------------
__global__ __launch_bounds__(256, 4) void main_kernel(
    const float* __restrict__ f, const float* __restrict__ W3,
    const float* __restrict__ Ap, const float* __restrict__ Cp,
    const ushort* __restrict__ W2f, const float* __restrict__ b2c,
    float* __restrict__ out)
{
  const int l    = threadIdx.x & 63;
  const int W    = blockIdx.x * 4 + (threadIdx.x >> 6);
  const int ib   = (W & 31) * 32;          // i-tile base
  const int j0   = (W >> 5) * JC;          // j-slice base
  const int half = l >> 5;
  const int c    = l & 31;
  const int b4   = half * 2;               // float4 offset of this lane's k-slice

  const bf16x8s* w2v = (const bf16x8s*)W2f;
  bf16x8s B0[4], B1[4];
  #pragma unroll
  for (int ks = 0; ks < 4; ++ks) {
    B0[ks] = w2v[((0 * 4 + ks) * 2 + half) * 32 + c];
    B1[ks] = w2v[((1 * 4 + ks) * 2 + half) * 32 + c];
  }

  const f32x4* arow = (const f32x4*)(Ap + (size_t)(ib + c) * HH);
  f32x4 A[8];
  #pragma unroll
  for (int ks = 0; ks < 4; ++ks) {
    A[ks * 2]     = arow[ks * 4 + b4];
    A[ks * 2 + 1] = arow[ks * 4 + b4 + 1];
  }

  const float cst0 = b2c[c],  cst1 = b2c[32 + c];
  const float w3m0 = -2.0f * DYF * W3[c], w3m1 = -2.0f * DYF * W3[32 + c];

  f32x16 u{};   // per-row u accumulators

#define LOADC(CR, jj) do {                                                  \
    const f32x4* crow = (const f32x4*)(Cp + (size_t)(jj) * HH);             \
    CR[0] = crow[b4];      CR[1] = crow[b4 + 1];                            \
    CR[2] = crow[4 + b4];  CR[3] = crow[4 + b4 + 1];                        \
    CR[4] = crow[8 + b4];  CR[5] = crow[8 + b4 + 1];                        \
    CR[6] = crow[12 + b4]; CR[7] = crow[12 + b4 + 1];                       \
  } while (0)

#define COMPUTE(CR, jj) do {                                                \
    float fjv = f[jj];                                                      \
    float wg0 = w3m0 * fjv, wg1 = w3m1 * fjv;                               \
    f32x16 acc0, acc1;                                                      \
    _Pragma("unroll")                                                       \
    for (int r = 0; r < 16; ++r) { acc0[r] = cst0; acc1[r] = cst1; }        \
    _Pragma("unroll")                                                       \
    for (int ks = 0; ks < 4; ++ks) {                                        \
      float t[8];                                                           \
      _Pragma("unroll")                                                     \
      for (int q = 0; q < 2; ++q) {                                         \
        f32x4 z = A[ks * 2 + q] + CR[ks * 2 + q];                           \
        _Pragma("unroll")                                                   \
        for (int e = 0; e < 4; ++e) {                                       \
          float ez = __builtin_amdgcn_exp2f(z[e]);                          \
          t[q * 4 + e] = __builtin_amdgcn_rcpf(ez + 1.0f);                  \
        }                                                                   \
      }                                                                     \
      union { bf16x8s s; __hip_bfloat162 h[4]; } fr;                        \
      fr.h[0] = __float22bfloat162_rn(make_float2(t[0], t[1]));             \
      fr.h[1] = __float22bfloat162_rn(make_float2(t[2], t[3]));             \
      fr.h[2] = __float22bfloat162_rn(make_float2(t[4], t[5]));             \
      fr.h[3] = __float22bfloat162_rn(make_float2(t[6], t[7]));             \
      acc0 = __builtin_amdgcn_mfma_f32_32x32x16_bf16(fr.s, B0[ks], acc0, 0, 0, 0); \
      acc1 = __builtin_amdgcn_mfma_f32_32x32x16_bf16(fr.s, B1[ks], acc1, 0, 0, 0); \
    }                                                                       \
    _Pragma("unroll")                                                       \
    for (int r = 0; r < 16; ++r) {                                          \
      float e0 = __builtin_amdgcn_exp2f(acc0[r]);                           \
      float r0 = __builtin_amdgcn_rcpf(e0 + 1.0f);                          \
      float e1 = __builtin_amdgcn_exp2f(acc1[r]);                           \
      float r1 = __builtin_amdgcn_rcpf(e1 + 1.0f);                          \
      u[r] = fmaf(r0, wg0, fmaf(r1, wg1, u[r]));                            \
    }                                                                       \
  } while (0)

  f32x4 CA[8], CB[8];
  LOADC(CA, j0);
  #pragma unroll 1
  for (int jj = 0; jj < JC; jj += 2) {
    LOADC(CB, j0 + jj + 1);
    COMPUTE(CA, j0 + jj);
    if (jj + 2 < JC) LOADC(CA, j0 + jj + 2);
    COMPUTE(CB, j0 + jj + 1);
  }

  #pragma unroll
  for (int r = 0; r < 16; ++r) {
    float v = u[r];
    v += __shfl_xor(v, 1);
    v += __shfl_xor(v, 2);
    v += __shfl_xor(v, 4);
    v += __shfl_xor(v, 8);
    v += __shfl_xor(v, 16);
    if (c == 0) {
      int row = (r & 3) + 8 * (r >> 2) + 4 * half;
      atomicAdd(&out[ib + row], v);
    }
  }
#undef LOADC
#undef COMPUTE
}

extern "C" void kernel_launch(void* const* d_in, const int* in_sizes, int n_in,
                              void* d_out, int out_size, void* d_ws, size_t ws_size,
                              hipStream_t stream) {
  const float* f   = (const float*)d_in[0];
  const float* ys  = (const float*)d_in[1];
  const float* W1  = (const float*)d_in[2];
  const float* b1  = (const float*)d_in[3];
  const float* W2  = (const float*)d_in[4];
  const float* b2  = (const float*)d_in[5];
  const float* W3  = (const float*)d_in[6];
  const float* b3  = (const float*)d_in[7];
  const float* Hw1 = (const float*)d_in[8];
  const float* Hb1 = (const float*)d_in[9];
  const float* Hw2 = (const float*)d_in[10];
  const float* Hb2 = (const float*)d_in[11];
  float* out = (float*)d_out;

  float*  Ap  = (float*)d_ws;                    // 1024*64 f32
  float*  Cp  = Ap + NN * HH;                    // 1024*64 f32
  ushort* W2f = (ushort*)(Cp + NN * HH);         // 4096 bf16
  float*  b2c = (float*)(W2f + 4096);            // 64 f32

  prep_kernel<<<69, 256, 0, stream>>>(ys, W1, b1, W2, b2, W3, b3, f,
                                      Hw1, Hb1, Hw2, Hb2, Ap, Cp, W2f, b2c, out);
  // 4096 waves: 32 i-tiles x 128 j-slices of JC=8 -> 4 waves/SIMD
  main_kernel<<<1024, 256, 0, stream>>>(f, W3, Ap, Cp, W2f, b2c, out);
}

// Round 4
// 50.543 us; speedup vs baseline: 3.3401x; 3.3401x over previous
//
#include <hip/hip_runtime.h>
#include <hip/hip_bf16.h>

#define NN  1024
#define HH  64
#define DYF 0.0009765625f            // 1/1024
#define SCL 2.8853900817779268f      // 2*log2(e): tanh(x) = 1 - 2/(2^(SCL*x)+1)
#define JC  8

typedef __attribute__((ext_vector_type(4)))  float f32x4;
typedef __attribute__((ext_vector_type(16))) float f32x16;
typedef __attribute__((ext_vector_type(8)))  short bf16x8s;

__device__ __forceinline__ float tfast(float x) {
  float e = __expf(2.0f * x);
  return 1.0f - __fdividef(2.0f, e + 1.0f);
}

// ---------------- fused prep ------------------------------------------------
// blocks 0..63 : Ea[i][m] = exp2(SCL*yi*W1[0][m]);
//                Ec[j][m] = exp2(SCL*(yj*W1[1][m]+b1[m]));
//                W2f = bf16(-2*SCL*W2) in B-fragment order
// blocks 64..67: out[i] = hom[i] + Hb2 + (b3 + sum(W3)) * G * DY   (G = sum f)
// block  68    : b2c[l] = SCL*(b2[l] + sum_m W2[m][l])
__global__ __launch_bounds__(256) void prep_kernel(
    const float* __restrict__ ys, const float* __restrict__ W1,
    const float* __restrict__ b1, const float* __restrict__ W2,
    const float* __restrict__ b2, const float* __restrict__ W3,
    const float* __restrict__ b3, const float* __restrict__ f,
    const float* __restrict__ Hw1, const float* __restrict__ Hb1,
    const float* __restrict__ Hw2, const float* __restrict__ Hb2,
    float* __restrict__ Ea, float* __restrict__ Ec,
    ushort* __restrict__ W2f, float* __restrict__ b2c,
    float* __restrict__ out)
{
  __shared__ float red[256];
  const int blk = blockIdx.x, t = threadIdx.x;

  if (blk < 64) {
    int gt = blk * 256 + t;                 // 0..16383
    int row = gt >> 4, part = gt & 15;
    float y = ys[row];
    #pragma unroll
    for (int q = 0; q < 4; ++q) {
      int m = part * 4 + q;
      Ea[row * HH + m] = __builtin_amdgcn_exp2f(SCL * y * W1[m]);
      Ec[row * HH + m] = __builtin_amdgcn_exp2f(SCL * fmaf(y, W1[HH + m], b1[m]));
    }
    if (gt < 4096) {
      // flat = (((tile*4+ks)*2+h)*32 + c)*8 + e ; val = -2*SCL*W2[k][tile*32+c]
      int e = gt & 7, c = (gt >> 3) & 31, h = (gt >> 8) & 1, ks = (gt >> 9) & 3, tl = gt >> 11;
      int k = ks * 16 + h * 8 + e;
      float v = -2.0f * SCL * W2[k * HH + tl * 32 + c];
      __hip_bfloat16 hb = __float2bfloat16(v);
      W2f[gt] = *reinterpret_cast<ushort*>(&hb);
    }
  } else if (blk < 68) {
    float4 fv = ((const float4*)f)[t];
    red[t] = fv.x + fv.y + fv.z + fv.w;
    __syncthreads();
    for (int s = 128; s > 0; s >>= 1) {
      if (t < s) red[t] += red[t + s];
      __syncthreads();
    }
    float G = red[0];
    int i = (blk - 64) * 256 + t;
    float y = ys[i];
    float hom = 0.0f, sw3 = 0.0f;
    #pragma unroll
    for (int l = 0; l < HH; ++l) {
      hom += Hw2[l] * tfast(fmaf(y, Hw1[l], Hb1[l]));
      sw3 += W3[l];
    }
    out[i] = hom + Hb2[0] + (b3[0] + sw3) * G * DYF;
  } else {
    if (t < HH) {
      float cs = 0.0f;
      #pragma unroll
      for (int m = 0; m < HH; ++m) cs += W2[m * HH + t];
      b2c[t] = SCL * (b2[t] + cs);
    }
  }
}

// ---------------- main: wave = 32 i's, loop over JC j's ---------------------
__global__ __launch_bounds__(256, 2) void main_kernel(
    const float* __restrict__ f, const float* __restrict__ W3,
    const float* __restrict__ Ea, const float* __restrict__ Ec,
    const ushort* __restrict__ W2f, const float* __restrict__ b2c,
    float* __restrict__ out)
{
  const int l    = threadIdx.x & 63;
  const int W    = blockIdx.x * 4 + (threadIdx.x >> 6);
  const int ib   = (W & 31) * 32;          // i-tile base
  const int j0   = (W >> 5) * JC;          // j-slice base
  const int half = l >> 5;
  const int c    = l & 31;
  const int b4   = half * 2;               // float4 offset of this lane's k-slice

  const bf16x8s* w2v = (const bf16x8s*)W2f;
  bf16x8s B0[4], B1[4];
  #pragma unroll
  for (int ks = 0; ks < 4; ++ks) {
    B0[ks] = w2v[((0 * 4 + ks) * 2 + half) * 32 + c];
    B1[ks] = w2v[((1 * 4 + ks) * 2 + half) * 32 + c];
  }

  // exp2(a') for this lane's row (i = ib + c), its 32 k-channels
  const f32x4* arow = (const f32x4*)(Ea + (size_t)(ib + c) * HH);
  f32x4 A[8];
  #pragma unroll
  for (int ks = 0; ks < 4; ++ks) {
    A[ks * 2]     = arow[ks * 4 + b4];
    A[ks * 2 + 1] = arow[ks * 4 + b4 + 1];
  }

  const float cst0 = b2c[c],  cst1 = b2c[32 + c];
  const float w3m0 = -2.0f * DYF * W3[c], w3m1 = -2.0f * DYF * W3[32 + c];

  f32x16 u{};   // per-row u accumulators

#define LOADC(CR, jj) do {                                                  \
    const f32x4* crow = (const f32x4*)(Ec + (size_t)(jj) * HH);             \
    CR[0] = crow[b4];      CR[1] = crow[b4 + 1];                            \
    CR[2] = crow[4 + b4];  CR[3] = crow[4 + b4 + 1];                        \
    CR[4] = crow[8 + b4];  CR[5] = crow[8 + b4 + 1];                        \
    CR[6] = crow[12 + b4]; CR[7] = crow[12 + b4 + 1];                       \
  } while (0)

#define COMPUTE(CR, jj) do {                                                \
    float fjv = f[jj];                                                      \
    float wg0 = w3m0 * fjv, wg1 = w3m1 * fjv;                               \
    f32x16 acc0, acc1;                                                      \
    _Pragma("unroll")                                                       \
    for (int r = 0; r < 16; ++r) { acc0[r] = cst0; acc1[r] = cst1; }        \
    _Pragma("unroll")                                                       \
    for (int ks = 0; ks < 4; ++ks) {                                        \
      float t[8];                                                           \
      _Pragma("unroll")                                                     \
      for (int q = 0; q < 2; ++q) {                                         \
        f32x4 ez = A[ks * 2 + q] * CR[ks * 2 + q];   /* exp2(a'+c') */      \
        _Pragma("unroll")                                                   \
        for (int e = 0; e < 4; ++e)                                         \
          t[q * 4 + e] = __builtin_amdgcn_rcpf(ez[e] + 1.0f);               \
      }                                                                     \
      union { bf16x8s s; __hip_bfloat162 h[4]; } fr;                        \
      fr.h[0] = __float22bfloat162_rn(make_float2(t[0], t[1]));             \
      fr.h[1] = __float22bfloat162_rn(make_float2(t[2], t[3]));             \
      fr.h[2] = __float22bfloat162_rn(make_float2(t[4], t[5]));             \
      fr.h[3] = __float22bfloat162_rn(make_float2(t[6], t[7]));             \
      acc0 = __builtin_amdgcn_mfma_f32_32x32x16_bf16(fr.s, B0[ks], acc0, 0, 0, 0); \
      acc1 = __builtin_amdgcn_mfma_f32_32x32x16_bf16(fr.s, B1[ks], acc1, 0, 0, 0); \
    }                                                                       \
    _Pragma("unroll")                                                       \
    for (int r = 0; r < 16; ++r) {                                          \
      float e0 = __builtin_amdgcn_exp2f(acc0[r]);                           \
      float r0 = __builtin_amdgcn_rcpf(e0 + 1.0f);                          \
      float e1 = __builtin_amdgcn_exp2f(acc1[r]);                           \
      float r1 = __builtin_amdgcn_rcpf(e1 + 1.0f);                          \
      u[r] = fmaf(r0, wg0, fmaf(r1, wg1, u[r]));                            \
    }                                                                       \
  } while (0)

  f32x4 CA[8], CB[8];
  LOADC(CA, j0);
  #pragma unroll 1
  for (int jj = 0; jj < JC; jj += 2) {
    LOADC(CB, j0 + jj + 1);
    COMPUTE(CA, j0 + jj);
    if (jj + 2 < JC) LOADC(CA, j0 + jj + 2);
    COMPUTE(CB, j0 + jj + 1);
  }

  #pragma unroll
  for (int r = 0; r < 16; ++r) {
    float v = u[r];
    v += __shfl_xor(v, 1);
    v += __shfl_xor(v, 2);
    v += __shfl_xor(v, 4);
    v += __shfl_xor(v, 8);
    v += __shfl_xor(v, 16);
    if (c == 0) {
      int row = (r & 3) + 8 * (r >> 2) + 4 * half;
      atomicAdd(&out[ib + row], v);
    }
  }
#undef LOADC
#undef COMPUTE
}

extern "C" void kernel_launch(void* const* d_in, const int* in_sizes, int n_in,
                              void* d_out, int out_size, void* d_ws, size_t ws_size,
                              hipStream_t stream) {
  const float* f   = (const float*)d_in[0];
  const float* ys  = (const float*)d_in[1];
  const float* W1  = (const float*)d_in[2];
  const float* b1  = (const float*)d_in[3];
  const float* W2  = (const float*)d_in[4];
  const float* b2  = (const float*)d_in[5];
  const float* W3  = (const float*)d_in[6];
  const float* b3  = (const float*)d_in[7];
  const float* Hw1 = (const float*)d_in[8];
  const float* Hb1 = (const float*)d_in[9];
  const float* Hw2 = (const float*)d_in[10];
  const float* Hb2 = (const float*)d_in[11];
  float* out = (float*)d_out;

  float*  Ea  = (float*)d_ws;                    // 1024*64 f32
  float*  Ecp = Ea + NN * HH;                    // 1024*64 f32
  ushort* W2f = (ushort*)(Ecp + NN * HH);        // 4096 bf16
  float*  b2c = (float*)(W2f + 4096);            // 64 f32

  prep_kernel<<<69, 256, 0, stream>>>(ys, W1, b1, W2, b2, W3, b3, f,
                                      Hw1, Hb1, Hw2, Hb2, Ea, Ecp, W2f, b2c, out);
  // 4096 waves: 32 i-tiles x 128 j-slices of JC=8 -> 4 waves/SIMD (by VGPR count)
  main_kernel<<<1024, 256, 0, stream>>>(f, W3, Ea, Ecp, W2f, b2c, out);
}

// Round 5
// 50.082 us; speedup vs baseline: 3.3708x; 1.0092x over previous
//
#include <hip/hip_runtime.h>
#include <hip/hip_bf16.h>

#define NN  1024
#define HH  64
#define DYF 0.0009765625f            // 1/1024
#define SCL 2.8853900817779268f      // 2*log2(e): tanh(x) = 1 - 2/(2^(SCL*x)+1)
#define JC  8

typedef __attribute__((ext_vector_type(4)))  float f32x4;
typedef __attribute__((ext_vector_type(16))) float f32x16;
typedef __attribute__((ext_vector_type(8)))  short bf16x8s;

__device__ __forceinline__ float tfast(float x) {
  float e = __expf(2.0f * x);
  return 1.0f - __fdividef(2.0f, e + 1.0f);
}

// ---------------- fused prep ------------------------------------------------
// blocks 0..63 : Ea[i][m] = exp2(SCL*yi*W1[0][m]);
//                Ec[j][m] = exp2(SCL*(yj*W1[1][m]+b1[m]));
//                W2f = bf16(-2*SCL*W2) in B-fragment order
// blocks 64..67: out[i] = hom[i] + Hb2 + (b3 + sum(W3)) * G * DY   (G = sum f)
// block  68    : b2c[l] = SCL*(b2[l] + sum_m W2[m][l])
__global__ __launch_bounds__(256) void prep_kernel(
    const float* __restrict__ ys, const float* __restrict__ W1,
    const float* __restrict__ b1, const float* __restrict__ W2,
    const float* __restrict__ b2, const float* __restrict__ W3,
    const float* __restrict__ b3, const float* __restrict__ f,
    const float* __restrict__ Hw1, const float* __restrict__ Hb1,
    const float* __restrict__ Hw2, const float* __restrict__ Hb2,
    float* __restrict__ Ea, float* __restrict__ Ec,
    ushort* __restrict__ W2f, float* __restrict__ b2c,
    float* __restrict__ out)
{
  __shared__ float red[256];
  const int blk = blockIdx.x, t = threadIdx.x;

  if (blk < 64) {
    int gt = blk * 256 + t;                 // 0..16383
    int row = gt >> 4, part = gt & 15;
    float y = ys[row];
    #pragma unroll
    for (int q = 0; q < 4; ++q) {
      int m = part * 4 + q;
      Ea[row * HH + m] = __builtin_amdgcn_exp2f(SCL * y * W1[m]);
      Ec[row * HH + m] = __builtin_amdgcn_exp2f(SCL * fmaf(y, W1[HH + m], b1[m]));
    }
    if (gt < 4096) {
      // flat = (((tile*4+ks)*2+h)*32 + c)*8 + e ; val = -2*SCL*W2[k][tile*32+c]
      int e = gt & 7, c = (gt >> 3) & 31, h = (gt >> 8) & 1, ks = (gt >> 9) & 3, tl = gt >> 11;
      int k = ks * 16 + h * 8 + e;
      float v = -2.0f * SCL * W2[k * HH + tl * 32 + c];
      __hip_bfloat16 hb = __float2bfloat16(v);
      W2f[gt] = *reinterpret_cast<ushort*>(&hb);
    }
  } else if (blk < 68) {
    float4 fv = ((const float4*)f)[t];
    red[t] = fv.x + fv.y + fv.z + fv.w;
    __syncthreads();
    for (int s = 128; s > 0; s >>= 1) {
      if (t < s) red[t] += red[t + s];
      __syncthreads();
    }
    float G = red[0];
    int i = (blk - 64) * 256 + t;
    float y = ys[i];
    float hom = 0.0f, sw3 = 0.0f;
    #pragma unroll
    for (int l = 0; l < HH; ++l) {
      hom += Hw2[l] * tfast(fmaf(y, Hw1[l], Hb1[l]));
      sw3 += W3[l];
    }
    out[i] = hom + Hb2[0] + (b3[0] + sw3) * G * DYF;
  } else {
    if (t < HH) {
      float cs = 0.0f;
      #pragma unroll
      for (int m = 0; m < HH; ++m) cs += W2[m * HH + t];
      b2c[t] = SCL * (b2[t] + cs);
    }
  }
}

// ---------------- main: 1-wave workgroup = 32 i's, loop over JC j's ---------
__global__ __launch_bounds__(64, 2) void main_kernel(
    const float* __restrict__ f, const float* __restrict__ W3,
    const float* __restrict__ Ea, const float* __restrict__ Ec,
    const ushort* __restrict__ W2f, const float* __restrict__ b2c,
    float* __restrict__ out)
{
  const int l    = threadIdx.x & 63;
  const int W    = blockIdx.x;             // one wave per block
  const int ib   = (W & 31) * 32;          // i-tile base
  const int j0   = (W >> 5) * JC;          // j-slice base
  const int half = l >> 5;
  const int c    = l & 31;
  const int b4   = half * 2;               // float4 offset of this lane's k-slice

  const bf16x8s* w2v = (const bf16x8s*)W2f;
  bf16x8s B0[4], B1[4];
  #pragma unroll
  for (int ks = 0; ks < 4; ++ks) {
    B0[ks] = w2v[((0 * 4 + ks) * 2 + half) * 32 + c];
    B1[ks] = w2v[((1 * 4 + ks) * 2 + half) * 32 + c];
  }

  // exp2(a') for this lane's row (i = ib + c), its 32 k-channels
  const f32x4* arow = (const f32x4*)(Ea + (size_t)(ib + c) * HH);
  f32x4 A[8];
  #pragma unroll
  for (int ks = 0; ks < 4; ++ks) {
    A[ks * 2]     = arow[ks * 4 + b4];
    A[ks * 2 + 1] = arow[ks * 4 + b4 + 1];
  }

  const float cst0 = b2c[c],  cst1 = b2c[32 + c];
  const float w3m0 = -2.0f * DYF * W3[c], w3m1 = -2.0f * DYF * W3[32 + c];

  f32x16 u{};   // per-row u accumulators

#define LOADC(CR, jj) do {                                                  \
    const f32x4* crow = (const f32x4*)(Ec + (size_t)(jj) * HH);             \
    CR[0] = crow[b4];      CR[1] = crow[b4 + 1];                            \
    CR[2] = crow[4 + b4];  CR[3] = crow[4 + b4 + 1];                        \
    CR[4] = crow[8 + b4];  CR[5] = crow[8 + b4 + 1];                        \
    CR[6] = crow[12 + b4]; CR[7] = crow[12 + b4 + 1];                       \
  } while (0)

#define COMPUTE(CR, jj) do {                                                \
    float fjv = f[jj];                                                      \
    float wg0 = w3m0 * fjv, wg1 = w3m1 * fjv;                               \
    f32x16 acc0, acc1;                                                      \
    _Pragma("unroll")                                                       \
    for (int r = 0; r < 16; ++r) { acc0[r] = cst0; acc1[r] = cst1; }        \
    _Pragma("unroll")                                                       \
    for (int ks = 0; ks < 4; ++ks) {                                        \
      float t[8];                                                           \
      _Pragma("unroll")                                                     \
      for (int q = 0; q < 2; ++q) {                                         \
        f32x4 ez = A[ks * 2 + q] * CR[ks * 2 + q];   /* exp2(a'+c') */      \
        _Pragma("unroll")                                                   \
        for (int e = 0; e < 4; ++e)                                         \
          t[q * 4 + e] = __builtin_amdgcn_rcpf(ez[e] + 1.0f);               \
      }                                                                     \
      union { bf16x8s s; __hip_bfloat162 h[4]; } fr;                        \
      fr.h[0] = __float22bfloat162_rn(make_float2(t[0], t[1]));             \
      fr.h[1] = __float22bfloat162_rn(make_float2(t[2], t[3]));             \
      fr.h[2] = __float22bfloat162_rn(make_float2(t[4], t[5]));             \
      fr.h[3] = __float22bfloat162_rn(make_float2(t[6], t[7]));             \
      acc0 = __builtin_amdgcn_mfma_f32_32x32x16_bf16(fr.s, B0[ks], acc0, 0, 0, 0); \
      acc1 = __builtin_amdgcn_mfma_f32_32x32x16_bf16(fr.s, B1[ks], acc1, 0, 0, 0); \
    }                                                                       \
    _Pragma("unroll")                                                       \
    for (int r = 0; r < 16; ++r) {                                          \
      float e0 = __builtin_amdgcn_exp2f(acc0[r]);                           \
      float r0 = __builtin_amdgcn_rcpf(e0 + 1.0f);                          \
      float e1 = __builtin_amdgcn_exp2f(acc1[r]);                           \
      float r1 = __builtin_amdgcn_rcpf(e1 + 1.0f);                          \
      u[r] = fmaf(r0, wg0, fmaf(r1, wg1, u[r]));                            \
    }                                                                       \
  } while (0)

  f32x4 CA[8], CB[8];
  LOADC(CA, j0);
  #pragma unroll 1
  for (int jj = 0; jj < JC; jj += 2) {
    LOADC(CB, j0 + jj + 1);
    COMPUTE(CA, j0 + jj);
    if (jj + 2 < JC) LOADC(CA, j0 + jj + 2);
    COMPUTE(CB, j0 + jj + 1);
  }

  #pragma unroll
  for (int r = 0; r < 16; ++r) {
    float v = u[r];
    v += __shfl_xor(v, 1);
    v += __shfl_xor(v, 2);
    v += __shfl_xor(v, 4);
    v += __shfl_xor(v, 8);
    v += __shfl_xor(v, 16);
    if (c == 0) {
      int row = (r & 3) + 8 * (r >> 2) + 4 * half;
      atomicAdd(&out[ib + row], v);
    }
  }
#undef LOADC
#undef COMPUTE
}

extern "C" void kernel_launch(void* const* d_in, const int* in_sizes, int n_in,
                              void* d_out, int out_size, void* d_ws, size_t ws_size,
                              hipStream_t stream) {
  const float* f   = (const float*)d_in[0];
  const float* ys  = (const float*)d_in[1];
  const float* W1  = (const float*)d_in[2];
  const float* b1  = (const float*)d_in[3];
  const float* W2  = (const float*)d_in[4];
  const float* b2  = (const float*)d_in[5];
  const float* W3  = (const float*)d_in[6];
  const float* b3  = (const float*)d_in[7];
  const float* Hw1 = (const float*)d_in[8];
  const float* Hb1 = (const float*)d_in[9];
  const float* Hw2 = (const float*)d_in[10];
  const float* Hb2 = (const float*)d_in[11];
  float* out = (float*)d_out;

  float*  Ea  = (float*)d_ws;                    // 1024*64 f32
  float*  Ecp = Ea + NN * HH;                    // 1024*64 f32
  ushort* W2f = (ushort*)(Ecp + NN * HH);        // 4096 bf16
  float*  b2c = (float*)(W2f + 4096);            // 64 f32

  prep_kernel<<<69, 256, 0, stream>>>(ys, W1, b1, W2, b2, W3, b3, f,
                                      Hw1, Hb1, Hw2, Hb2, Ea, Ecp, W2f, b2c, out);
  // 4096 single-wave workgroups: 32 i-tiles x 128 j-slices of JC=8
  main_kernel<<<4096, 64, 0, stream>>>(f, W3, Ea, Ecp, W2f, b2c, out);
}